// Round 1
// baseline (1219.316 us; speedup 1.0000x reference)
//
#include <hip/hip_runtime.h>
#include <hip/hip_bf16.h>

// DeepSeek MoE: B=2,T=2048,D=2048,H=1408,E=16,S=2,TOP_K=2
// T_tot = 4096 tokens. Out = [4096*2048 f32] ++ [aux f32]  (8388609 floats)

#define T_TOT   4096
#define DMODEL  2048
#define HDIM    1408
#define NEXP    16
#define MAXSLOT 10240   // 8192 real slots + up to 16*127 pad, rounded: 80 tiles * 128
#define MAXTILE 80

typedef short     bf16x8_t __attribute__((ext_vector_type(8)));
typedef float     f32x4_t  __attribute__((ext_vector_type(4)));

__device__ __forceinline__ ushort f2bf(float f) {
    unsigned u = __float_as_uint(f);
    u += 0x7fffu + ((u >> 16) & 1u);   // RNE
    return (ushort)(u >> 16);
}
__device__ __forceinline__ float silu(float v) { return v / (1.0f + __expf(-v)); }

__device__ __forceinline__ void async16(const ushort* g, ushort* l) {
    __builtin_amdgcn_global_load_lds((const __attribute__((address_space(1))) void*)g,
                                     (__attribute__((address_space(3))) void*)l, 16, 0, 0);
}

// ---------------- small utility kernels ----------------

__global__ void init_kernel(int* cnt, double* ps, double* ls) {
    if (threadIdx.x < NEXP) { cnt[threadIdx.x] = 0; ps[threadIdx.x] = 0.0; ls[threadIdx.x] = 0.0; }
}

__global__ __launch_bounds__(256) void cvt_bf16(const float* __restrict__ src, ushort* __restrict__ dst) {
    size_t i = ((size_t)blockIdx.x * 256 + threadIdx.x) * 4;
    float4 v = *(const float4*)(src + i);
    ushort4 o; o.x = f2bf(v.x); o.y = f2bf(v.y); o.z = f2bf(v.z); o.w = f2bf(v.w);
    *(ushort4*)(dst + i) = o;
}

// src [R,C] f32 (batched) -> dst [C,R] bf16 with dst row-stride ldd, batch offsets
__global__ __launch_bounds__(256) void transpose_cvt(const float* __restrict__ src, ushort* __restrict__ dst,
                                                     int R, int C, long sbatch, long dbatch, int ldd) {
    __shared__ float t[32][33];
    const float* s = src + (long)blockIdx.z * sbatch;
    ushort* d = dst + (long)blockIdx.z * dbatch;
    int c0 = blockIdx.x * 32, r0 = blockIdx.y * 32;
    int tx = threadIdx.x, ty = threadIdx.y;   // (32,8)
#pragma unroll
    for (int i = 0; i < 4; i++) {
        int r = r0 + ty + i * 8;
        t[ty + i * 8][tx] = s[(size_t)r * C + c0 + tx];
    }
    __syncthreads();
#pragma unroll
    for (int i = 0; i < 4; i++) {
        int c = c0 + ty + i * 8;
        d[(size_t)c * ldd + r0 + tx] = f2bf(t[tx][ty + i * 8]);
    }
}

// ---------------- router (fp64 accumulate for exact ranking + aux) ----------------

__global__ __launch_bounds__(256) void router_kernel(const float* __restrict__ x, const float* __restrict__ gw,
                                                     int* __restrict__ topk_idx, float* __restrict__ topk_w,
                                                     double* __restrict__ probs_sum, double* __restrict__ logits_sum,
                                                     int* __restrict__ cnt) {
    int wv = threadIdx.x >> 6, l = threadIdx.x & 63;
    int t = blockIdx.x * 4 + wv;
    double acc[NEXP];
#pragma unroll
    for (int e = 0; e < NEXP; e++) acc[e] = 0.0;
    const float* xr = x + (size_t)t * DMODEL;
    for (int i = 0; i < DMODEL / 64; i++) {
        int d = i * 64 + l;
        double xv = (double)xr[d];
        const float4* g = (const float4*)(gw + (size_t)d * NEXP);
        float4 g0 = g[0], g1 = g[1], g2 = g[2], g3 = g[3];
        acc[0]  += xv * (double)g0.x; acc[1]  += xv * (double)g0.y;
        acc[2]  += xv * (double)g0.z; acc[3]  += xv * (double)g0.w;
        acc[4]  += xv * (double)g1.x; acc[5]  += xv * (double)g1.y;
        acc[6]  += xv * (double)g1.z; acc[7]  += xv * (double)g1.w;
        acc[8]  += xv * (double)g2.x; acc[9]  += xv * (double)g2.y;
        acc[10] += xv * (double)g2.z; acc[11] += xv * (double)g2.w;
        acc[12] += xv * (double)g3.x; acc[13] += xv * (double)g3.y;
        acc[14] += xv * (double)g3.z; acc[15] += xv * (double)g3.w;
    }
#pragma unroll
    for (int off = 32; off; off >>= 1)
#pragma unroll
        for (int e = 0; e < NEXP; e++) acc[e] += __shfl_down(acc[e], off);

    __shared__ double bp[4][NEXP], bl[4][NEXP];
    if (l == 0) {
        double m = acc[0];
#pragma unroll
        for (int e = 1; e < NEXP; e++) m = acc[e] > m ? acc[e] : m;
        double p[NEXP], s = 0.0;
#pragma unroll
        for (int e = 0; e < NEXP; e++) { p[e] = exp(acc[e] - m); s += p[e]; }
#pragma unroll
        for (int e = 0; e < NEXP; e++) p[e] /= s;
        int e1 = 0;
#pragma unroll
        for (int e = 1; e < NEXP; e++) if (p[e] > p[e1]) e1 = e;
        int e2 = (e1 == 0) ? 1 : 0;
#pragma unroll
        for (int e = 0; e < NEXP; e++) if (e != e1 && p[e] > p[e2]) e2 = e;
        double s2 = p[e1] + p[e2];
        topk_idx[t * 2] = e1; topk_idx[t * 2 + 1] = e2;
        topk_w[t * 2] = (float)(p[e1] / s2); topk_w[t * 2 + 1] = (float)(p[e2] / s2);
        atomicAdd(&cnt[e1], 1); atomicAdd(&cnt[e2], 1);
#pragma unroll
        for (int e = 0; e < NEXP; e++) { bp[wv][e] = p[e]; bl[wv][e] = acc[e]; }
    }
    __syncthreads();
    if (threadIdx.x < NEXP) {
        int e = threadIdx.x;
        atomicAdd(&probs_sum[e], bp[0][e] + bp[1][e] + bp[2][e] + bp[3][e]);
        atomicAdd(&logits_sum[e], bl[0][e] + bl[1][e] + bl[2][e] + bl[3][e]);
    }
}

// build tile tables, cursors, init slot arrays, write aux loss
__global__ void setup_kernel(const int* __restrict__ cnt, int* __restrict__ cursor,
                             int* __restrict__ tile_expert, int* __restrict__ tile_row, int* __restrict__ meta,
                             int* __restrict__ slot_token, float* __restrict__ slot_w,
                             const double* __restrict__ probs_sum, const double* __restrict__ logits_sum,
                             float* __restrict__ out_aux) {
    if (threadIdx.x == 0) {
        int off = 0, nt = 0;
        for (int e = 0; e < NEXP; e++) {
            cursor[e] = off;
            int tiles = (cnt[e] + 127) >> 7;
            for (int j = 0; j < tiles; j++) { tile_expert[nt] = e; tile_row[nt] = off + j * 128; nt++; }
            off += tiles * 128;
        }
        meta[0] = nt; meta[1] = off;
        double aux = 0.0;
        for (int e = 0; e < NEXP; e++)
            aux += (probs_sum[e] / (double)T_TOT) * (logits_sum[e] / (double)T_TOT);
        out_aux[0] = (float)(aux * (double)NEXP);
    }
    __syncthreads();
    for (int i = threadIdx.x; i < MAXSLOT; i += 256) { slot_token[i] = 0; slot_w[i] = 0.0f; }
}

__global__ void scatter_kernel(const int* __restrict__ topk_idx, const float* __restrict__ topk_w,
                               int* __restrict__ cursor, int* __restrict__ slot_token, float* __restrict__ slot_w) {
    int t = blockIdx.x * 256 + threadIdx.x;
#pragma unroll
    for (int k = 0; k < 2; k++) {
        int e = topk_idx[t * 2 + k];
        int pos = atomicAdd(&cursor[e], 1);
        slot_token[pos] = t;
        slot_w[pos] = topk_w[t * 2 + k];
    }
}

// ---------------- GEMM core: 128x128 tile, BK=32, 4 waves, mfma 16x16x32 bf16 ----------------
// A [*,K] bf16 row-major (lda), B [N,K] bf16 row-major (ldb, i.e. B^T of math B).
// LDS: As 128x32 (8KB) + Bs 128x32 (8KB), staged via global_load_lds dwordx4.

template<bool INDIRECT_A>
__device__ __forceinline__ void gemm_tile_core(const ushort* __restrict__ A, const ushort* __restrict__ B,
                                               int lda, int ldb, int K, int m0, int n0,
                                               const int* __restrict__ rowmap,
                                               f32x4_t acc[4][4], ushort* lds) {
    const int tid = threadIdx.x;
    const int w = tid >> 6, l = tid & 63;
    const int c0 = w * 2, c1 = c0 + 1;       // each wave stages 2 of 8 1KB chunks per tile
    const int subrow = l >> 2;               // 0..15 within chunk
    const int kc = (l & 3) * 8;              // bf16 element offset within 32-wide K row
    int ar0 = c0 * 16 + subrow, ar1 = c1 * 16 + subrow;
    long ga0, ga1;
    if (INDIRECT_A) { ga0 = (long)rowmap[m0 + ar0]; ga1 = (long)rowmap[m0 + ar1]; }
    else            { ga0 = (long)(m0 + ar0);       ga1 = (long)(m0 + ar1); }
    const ushort* pa0 = A + ga0 * lda + kc;
    const ushort* pa1 = A + ga1 * lda + kc;
    const ushort* pb0 = B + (long)(n0 + ar0) * ldb + kc;
    const ushort* pb1 = B + (long)(n0 + ar1) * ldb + kc;
    ushort* la0 = lds + c0 * 512;
    ushort* la1 = lds + c1 * 512;
    ushort* lb0 = lds + 4096 + c0 * 512;
    ushort* lb1 = lds + 4096 + c1 * 512;
    const int wm = w & 1, wn = w >> 1;
    const int lrow = l & 15, quad = l >> 4;
    const ushort* As = lds;
    const ushort* Bs = lds + 4096;

    for (int kt = 0; kt < K; kt += 32) {
        async16(pa0, la0); async16(pa1, la1);
        async16(pb0, lb0); async16(pb1, lb1);
        pa0 += 32; pa1 += 32; pb0 += 32; pb1 += 32;
        __syncthreads();   // drains vmcnt: staged tile visible
        bf16x8_t a[4], b[4];
#pragma unroll
        for (int mi = 0; mi < 4; mi++)
            a[mi] = *(const bf16x8_t*)(As + (wm * 64 + mi * 16 + lrow) * 32 + quad * 8);
#pragma unroll
        for (int ni = 0; ni < 4; ni++)
            b[ni] = *(const bf16x8_t*)(Bs + (wn * 64 + ni * 16 + lrow) * 32 + quad * 8);
#pragma unroll
        for (int mi = 0; mi < 4; mi++)
#pragma unroll
            for (int ni = 0; ni < 4; ni++)
                acc[mi][ni] = __builtin_amdgcn_mfma_f32_16x16x32_bf16(a[mi], b[ni], acc[mi][ni], 0, 0, 0);
        __syncthreads();   // all waves done reading before next stage overwrites
    }
}

// MODE 0: silu -> bf16 store (shared GEMM1, z-batched over S). MODE 2: f32 store (shared GEMM2).
template<int MODE>
__global__ __launch_bounds__(256, 2) void gemm_dense(const ushort* __restrict__ A, const ushort* __restrict__ B,
                                                     void* __restrict__ C, int lda, int ldb, int ldc, int K,
                                                     long bStride, int cZOff) {
    __shared__ ushort lds[8192];
    int m0 = blockIdx.x * 128, n0 = blockIdx.y * 128;
    const ushort* Bz = B + (long)blockIdx.z * bStride;
    f32x4_t acc[4][4];
#pragma unroll
    for (int mi = 0; mi < 4; mi++)
#pragma unroll
        for (int ni = 0; ni < 4; ni++) acc[mi][ni] = (f32x4_t){0.f, 0.f, 0.f, 0.f};
    gemm_tile_core<false>(A, Bz, lda, ldb, K, m0, n0, nullptr, acc, lds);

    const int w = threadIdx.x >> 6, l = threadIdx.x & 63;
    const int wm = w & 1, wn = w >> 1, quad = l >> 4, lcol = l & 15;
    int colBase = (int)blockIdx.z * cZOff + n0 + wn * 64;
#pragma unroll
    for (int mi = 0; mi < 4; mi++) {
        int rowb = m0 + wm * 64 + mi * 16 + quad * 4;
#pragma unroll
        for (int ni = 0; ni < 4; ni++) {
            int col = colBase + ni * 16 + lcol;
#pragma unroll
            for (int r = 0; r < 4; r++) {
                float v = acc[mi][ni][r];
                if (MODE == 0) ((ushort*)C)[(long)(rowb + r) * ldc + col] = f2bf(silu(v));
                else           ((float*)C)[(long)(rowb + r) * ldc + col] = v;
            }
        }
    }
}

// MODE 1: routed GEMM1 — A rows gathered via slot_token, silu -> bf16 to hg (slot-major).
// MODE 3: routed GEMM2 — A = hg direct, epilogue scatters w * acc into out[token] via atomicAdd.
template<int MODE>
__global__ __launch_bounds__(256, 2) void gemm_grouped(const ushort* __restrict__ A, const ushort* __restrict__ B,
                                                       void* __restrict__ C, int lda, int ldb, int ldc, int K,
                                                       long bExpertStride,
                                                       const int* __restrict__ tile_expert,
                                                       const int* __restrict__ tile_row,
                                                       const int* __restrict__ meta,
                                                       const int* __restrict__ slot_token,
                                                       const float* __restrict__ slot_w) {
    if ((int)blockIdx.x >= meta[0]) return;
    __shared__ ushort lds[8192];
    int e = tile_expert[blockIdx.x];
    int m0 = tile_row[blockIdx.x];
    int n0 = blockIdx.y * 128;
    const ushort* Be = B + (long)e * bExpertStride;
    f32x4_t acc[4][4];
#pragma unroll
    for (int mi = 0; mi < 4; mi++)
#pragma unroll
        for (int ni = 0; ni < 4; ni++) acc[mi][ni] = (f32x4_t){0.f, 0.f, 0.f, 0.f};
    gemm_tile_core<MODE == 1>(A, Be, lda, ldb, K, m0, n0, slot_token, acc, lds);

    const int w = threadIdx.x >> 6, l = threadIdx.x & 63;
    const int wm = w & 1, wn = w >> 1, quad = l >> 4, lcol = l & 15;
#pragma unroll
    for (int mi = 0; mi < 4; mi++) {
        int rowb = m0 + wm * 64 + mi * 16 + quad * 4;
#pragma unroll
        for (int ni = 0; ni < 4; ni++) {
            int col = n0 + wn * 64 + ni * 16 + lcol;
#pragma unroll
            for (int r = 0; r < 4; r++) {
                float v = acc[mi][ni][r];
                if (MODE == 1) {
                    ((ushort*)C)[(long)(rowb + r) * ldc + col] = f2bf(silu(v));
                } else {
                    int row = rowb + r;
                    int tok = slot_token[row];
                    float wt = slot_w[row];     // 0 for pad slots -> adds exactly 0
                    atomicAdd(&((float*)C)[(long)tok * ldc + col], v * wt);
                }
            }
        }
    }
}

// ---------------- launch ----------------

extern "C" void kernel_launch(void* const* d_in, const int* in_sizes, int n_in,
                              void* d_out, int out_size, void* d_ws, size_t ws_size,
                              hipStream_t stream) {
    const float* x   = (const float*)d_in[0];
    const float* gw  = (const float*)d_in[1];
    const float* sw1 = (const float*)d_in[2];
    const float* sw2 = (const float*)d_in[3];
    const float* ew1 = (const float*)d_in[4];
    const float* ew2 = (const float*)d_in[5];
    float* out = (float*)d_out;

    char* p = (char*)d_ws;
    auto alloc = [&](size_t bytes) { char* r = p; p += (bytes + 511) & ~(size_t)511; return r; };
    ushort* xb    = (ushort*)alloc((size_t)T_TOT * DMODEL * 2);          // x bf16 [4096,2048]
    ushort* w1t   = (ushort*)alloc((size_t)2 * HDIM * DMODEL * 2);       // [s][h][d]
    ushort* w2t   = (ushort*)alloc((size_t)DMODEL * 2 * HDIM * 2);       // [d][s*1408+h]
    ushort* ew1t  = (ushort*)alloc((size_t)NEXP * HDIM * DMODEL * 2);    // [e][h][d]
    ushort* ew2t  = (ushort*)alloc((size_t)NEXP * DMODEL * HDIM * 2);    // [e][d][h]
    ushort* h     = (ushort*)alloc((size_t)T_TOT * 2 * HDIM * 2);        // shared act [4096,2816]
    ushort* hg    = (ushort*)alloc((size_t)MAXSLOT * HDIM * 2);          // routed act [10240,1408]
    int*    slot_token = (int*)alloc(MAXSLOT * 4);
    float*  slot_w     = (float*)alloc(MAXSLOT * 4);
    int*    topk_idx   = (int*)alloc(T_TOT * 2 * 4);
    float*  topk_w     = (float*)alloc(T_TOT * 2 * 4);
    int*    cnt        = (int*)alloc(64);
    int*    cursor     = (int*)alloc(64);
    int*    tile_expert= (int*)alloc(512);
    int*    tile_row   = (int*)alloc(512);
    int*    meta       = (int*)alloc(64);
    double* probs_sum  = (double*)alloc(128);
    double* logits_sum = (double*)alloc(128);

    init_kernel<<<1, 64, 0, stream>>>(cnt, probs_sum, logits_sum);
    cvt_bf16<<<(T_TOT * DMODEL) / 1024, 256, 0, stream>>>(x, xb);
    // shared_w1 [2,2048,1408] -> w1t [2,1408,2048]
    transpose_cvt<<<dim3(HDIM / 32, DMODEL / 32, 2), dim3(32, 8), 0, stream>>>(
        sw1, w1t, DMODEL, HDIM, (long)DMODEL * HDIM, (long)HDIM * DMODEL, DMODEL);
    // shared_w2 [2,1408,2048] -> w2t [2048, 2*1408] (s blocks side by side in K)
    transpose_cvt<<<dim3(DMODEL / 32, HDIM / 32, 2), dim3(32, 8), 0, stream>>>(
        sw2, w2t, HDIM, DMODEL, (long)HDIM * DMODEL, (long)HDIM, 2 * HDIM);
    // expert_w1 [16,2048,1408] -> ew1t [16,1408,2048]
    transpose_cvt<<<dim3(HDIM / 32, DMODEL / 32, NEXP), dim3(32, 8), 0, stream>>>(
        ew1, ew1t, DMODEL, HDIM, (long)DMODEL * HDIM, (long)HDIM * DMODEL, DMODEL);
    // expert_w2 [16,1408,2048] -> ew2t [16,2048,1408]
    transpose_cvt<<<dim3(DMODEL / 32, HDIM / 32, NEXP), dim3(32, 8), 0, stream>>>(
        ew2, ew2t, HDIM, DMODEL, (long)HDIM * DMODEL, (long)DMODEL * HDIM, HDIM);

    router_kernel<<<T_TOT / 4, 256, 0, stream>>>(x, gw, topk_idx, topk_w, probs_sum, logits_sum, cnt);
    setup_kernel<<<1, 256, 0, stream>>>(cnt, cursor, tile_expert, tile_row, meta,
                                        slot_token, slot_w, probs_sum, logits_sum, out + (size_t)T_TOT * DMODEL);
    scatter_kernel<<<T_TOT / 256, 256, 0, stream>>>(topk_idx, topk_w, cursor, slot_token, slot_w);

    // shared GEMM1: h[t, s*1408+j] = silu(xb @ w1t[s]^T)   grid (32, 11, 2)
    gemm_dense<0><<<dim3(T_TOT / 128, HDIM / 128, 2), 256, 0, stream>>>(
        xb, w1t, h, DMODEL, DMODEL, 2 * HDIM, DMODEL, (long)HDIM * DMODEL, HDIM);
    // routed GEMM1: hg[slot, j] = silu(x[slot_token] @ ew1t[e]^T)   grid (80, 11)
    gemm_grouped<1><<<dim3(MAXTILE, HDIM / 128), 256, 0, stream>>>(
        xb, ew1t, hg, DMODEL, DMODEL, HDIM, DMODEL, (long)HDIM * DMODEL,
        tile_expert, tile_row, meta, slot_token, slot_w);
    // shared GEMM2: out[t,d] = h @ w2t^T  (K = 2816 covers both shared experts)   grid (32, 16)
    gemm_dense<2><<<dim3(T_TOT / 128, DMODEL / 128, 1), 256, 0, stream>>>(
        h, w2t, out, 2 * HDIM, 2 * HDIM, DMODEL, 2 * HDIM, 0L, 0);
    // routed GEMM2: out[token,d] += w_slot * (hg @ ew2t[e]^T)   grid (80, 16), atomic
    gemm_grouped<3><<<dim3(MAXTILE, DMODEL / 128), 256, 0, stream>>>(
        hg, ew2t, out, HDIM, HDIM, DMODEL, HDIM, (long)DMODEL * HDIM,
        tile_expert, tile_row, meta, slot_token, slot_w);
}

// Round 2
// 957.742 us; speedup vs baseline: 1.2731x; 1.2731x over previous
//
#include <hip/hip_runtime.h>
#include <hip/hip_bf16.h>

// DeepSeek MoE: B=2,T=2048,D=2048,H=1408,E=16,S=2,TOP_K=2
// T_tot = 4096 tokens. Out = [4096*2048 f32] ++ [aux f32]

#define T_TOT   4096
#define DMODEL  2048
#define HDIM    1408
#define NEXP    16
#define MAXSLOT 10240   // 8192 real slots + pad to 128 per expert
#define MAXTILE 80

typedef short     bf16x8_t  __attribute__((ext_vector_type(8)));
typedef float     f32x4_t   __attribute__((ext_vector_type(4)));
typedef ushort    u16x8_t   __attribute__((ext_vector_type(8)));

__device__ __forceinline__ ushort f2bf(float f) {
    unsigned u = __float_as_uint(f);
    u += 0x7fffu + ((u >> 16) & 1u);   // RNE
    return (ushort)(u >> 16);
}
__device__ __forceinline__ float bf2f(ushort b) { return __uint_as_float((unsigned)b << 16); }
__device__ __forceinline__ float silu(float v) { return v / (1.0f + __expf(-v)); }

__device__ __forceinline__ void async16(const ushort* g, ushort* l) {
    __builtin_amdgcn_global_load_lds((const __attribute__((address_space(1))) void*)g,
                                     (__attribute__((address_space(3))) void*)l, 16, 0, 0);
}

// ---------------- small utility kernels ----------------

__global__ void init_kernel(int* cnt, double* ps, double* ls) {
    if (threadIdx.x < NEXP) { cnt[threadIdx.x] = 0; ps[threadIdx.x] = 0.0; ls[threadIdx.x] = 0.0; }
}

__global__ __launch_bounds__(256) void cvt_bf16(const float* __restrict__ src, ushort* __restrict__ dst) {
    size_t i = ((size_t)blockIdx.x * 256 + threadIdx.x) * 4;
    float4 v = *(const float4*)(src + i);
    ushort4 o; o.x = f2bf(v.x); o.y = f2bf(v.y); o.z = f2bf(v.z); o.w = f2bf(v.w);
    *(ushort4*)(dst + i) = o;
}

// src [R,C] f32 (batched) -> dst [C,R] bf16, dst row-stride ldd. 64x64 tiles.
// Read: 16 lanes x float4 = 256B rows. Write: 8 lanes x 16B = 128B rows.
__global__ __launch_bounds__(256) void transpose_cvt(const float* __restrict__ src, ushort* __restrict__ dst,
                                                     int R, int C, long sbatch, long dbatch, int ldd) {
    __shared__ ushort t[64][72];   // +8 ushort pad breaks bank-conflict stride
    const float* s = src + (long)blockIdx.z * sbatch;
    ushort* d = dst + (long)blockIdx.z * dbatch;
    int c0 = blockIdx.x * 64, r0 = blockIdx.y * 64;
    int tx = threadIdx.x & 15, ty = threadIdx.x >> 4;
#pragma unroll
    for (int i = 0; i < 4; i++) {
        int r = ty + i * 16;
        float4 v = *(const float4*)(s + (size_t)(r0 + r) * C + c0 + tx * 4);
        ushort4 o; o.x = f2bf(v.x); o.y = f2bf(v.y); o.z = f2bf(v.z); o.w = f2bf(v.w);
        *(ushort4*)&t[r][tx * 4] = o;
    }
    __syncthreads();
    int cx = threadIdx.x & 7, cy = threadIdx.x >> 3;
#pragma unroll
    for (int i = 0; i < 2; i++) {
        int cc = cy + i * 32;
        u16x8_t o;
#pragma unroll
        for (int j = 0; j < 8; j++) o[j] = t[cx * 8 + j][cc];
        *(u16x8_t*)(d + (size_t)(c0 + cc) * ldd + r0 + cx * 8) = o;
    }
}

// ---------------- router (fp64 accumulate for exact ranking + aux) ----------------

__global__ __launch_bounds__(256) void router_kernel(const float* __restrict__ x, const float* __restrict__ gw,
                                                     int* __restrict__ topk_idx, float* __restrict__ topk_w,
                                                     double* __restrict__ probs_sum, double* __restrict__ logits_sum,
                                                     int* __restrict__ cnt) {
    int wv = threadIdx.x >> 6, l = threadIdx.x & 63;
    int t = blockIdx.x * 4 + wv;
    double acc[NEXP];
#pragma unroll
    for (int e = 0; e < NEXP; e++) acc[e] = 0.0;
    const float* xr = x + (size_t)t * DMODEL;
    for (int i = 0; i < DMODEL / 64; i++) {
        int d = i * 64 + l;
        double xv = (double)xr[d];
        const float4* g = (const float4*)(gw + (size_t)d * NEXP);
        float4 g0 = g[0], g1 = g[1], g2 = g[2], g3 = g[3];
        acc[0]  += xv * (double)g0.x; acc[1]  += xv * (double)g0.y;
        acc[2]  += xv * (double)g0.z; acc[3]  += xv * (double)g0.w;
        acc[4]  += xv * (double)g1.x; acc[5]  += xv * (double)g1.y;
        acc[6]  += xv * (double)g1.z; acc[7]  += xv * (double)g1.w;
        acc[8]  += xv * (double)g2.x; acc[9]  += xv * (double)g2.y;
        acc[10] += xv * (double)g2.z; acc[11] += xv * (double)g2.w;
        acc[12] += xv * (double)g3.x; acc[13] += xv * (double)g3.y;
        acc[14] += xv * (double)g3.z; acc[15] += xv * (double)g3.w;
    }
#pragma unroll
    for (int off = 32; off; off >>= 1)
#pragma unroll
        for (int e = 0; e < NEXP; e++) acc[e] += __shfl_down(acc[e], off);

    __shared__ double bp[4][NEXP], bl[4][NEXP];
    if (l == 0) {
        double m = acc[0];
#pragma unroll
        for (int e = 1; e < NEXP; e++) m = acc[e] > m ? acc[e] : m;
        double p[NEXP], s = 0.0;
#pragma unroll
        for (int e = 0; e < NEXP; e++) { p[e] = exp(acc[e] - m); s += p[e]; }
#pragma unroll
        for (int e = 0; e < NEXP; e++) p[e] /= s;
        int e1 = 0;
#pragma unroll
        for (int e = 1; e < NEXP; e++) if (p[e] > p[e1]) e1 = e;
        int e2 = (e1 == 0) ? 1 : 0;
#pragma unroll
        for (int e = 0; e < NEXP; e++) if (e != e1 && p[e] > p[e2]) e2 = e;
        double s2 = p[e1] + p[e2];
        topk_idx[t * 2] = e1; topk_idx[t * 2 + 1] = e2;
        topk_w[t * 2] = (float)(p[e1] / s2); topk_w[t * 2 + 1] = (float)(p[e2] / s2);
        atomicAdd(&cnt[e1], 1); atomicAdd(&cnt[e2], 1);
#pragma unroll
        for (int e = 0; e < NEXP; e++) { bp[wv][e] = p[e]; bl[wv][e] = acc[e]; }
    }
    __syncthreads();
    if (threadIdx.x < NEXP) {
        int e = threadIdx.x;
        atomicAdd(&probs_sum[e], bp[0][e] + bp[1][e] + bp[2][e] + bp[3][e]);
        atomicAdd(&logits_sum[e], bl[0][e] + bl[1][e] + bl[2][e] + bl[3][e]);
    }
}

__global__ void setup_kernel(const int* __restrict__ cnt, int* __restrict__ cursor,
                             int* __restrict__ tile_expert, int* __restrict__ tile_row, int* __restrict__ meta,
                             int* __restrict__ slot_token, float* __restrict__ slot_w,
                             const double* __restrict__ probs_sum, const double* __restrict__ logits_sum,
                             float* __restrict__ out_aux) {
    if (threadIdx.x == 0) {
        int off = 0, nt = 0;
        for (int e = 0; e < NEXP; e++) {
            cursor[e] = off;
            int tiles = (cnt[e] + 127) >> 7;
            for (int j = 0; j < tiles; j++) { tile_expert[nt] = e; tile_row[nt] = off + j * 128; nt++; }
            off += tiles * 128;
        }
        meta[0] = nt; meta[1] = off;
        double aux = 0.0;
        for (int e = 0; e < NEXP; e++)
            aux += (probs_sum[e] / (double)T_TOT) * (logits_sum[e] / (double)T_TOT);
        out_aux[0] = (float)(aux * (double)NEXP);
    }
    __syncthreads();
    for (int i = threadIdx.x; i < MAXSLOT; i += 256) { slot_token[i] = 0; slot_w[i] = 0.0f; }
}

__global__ void scatter_kernel(const int* __restrict__ topk_idx, const float* __restrict__ topk_w,
                               int* __restrict__ cursor, int* __restrict__ slot_token, float* __restrict__ slot_w,
                               int* __restrict__ slot_of) {
    int t = blockIdx.x * 256 + threadIdx.x;
#pragma unroll
    for (int k = 0; k < 2; k++) {
        int e = topk_idx[t * 2 + k];
        int pos = atomicAdd(&cursor[e], 1);
        slot_token[pos] = t;
        slot_w[pos] = topk_w[t * 2 + k];
        slot_of[t * 2 + k] = pos;
    }
}

// ---------------- GEMM core: 128x128 tile, BK=32, 4 waves, mfma 16x16x32 bf16 ----------------
// Double-buffered LDS (2 x 16KB halves), ONE barrier per K-iter: prefetch tile k+1
// into the other half before computing tile k, so the barrier's vmcnt(0) drain
// lands after a full compute phase of overlap.

template<bool INDIRECT_A>
__device__ __forceinline__ void gemm_tile_core(const ushort* __restrict__ A, const ushort* __restrict__ B,
                                               int lda, int ldb, int K, int m0, int n0,
                                               const int* __restrict__ rowmap,
                                               f32x4_t acc[4][4], ushort* lds) {
    const int tid = threadIdx.x;
    const int w = tid >> 6, l = tid & 63;
    const int c0 = w * 2, c1 = c0 + 1;       // each wave stages 2 of 8 1KB chunks of A and of B
    const int subrow = l >> 2;
    const int kc = (l & 3) * 8;
    int ar0 = c0 * 16 + subrow, ar1 = c1 * 16 + subrow;
    long ga0, ga1;
    if (INDIRECT_A) { ga0 = (long)rowmap[m0 + ar0]; ga1 = (long)rowmap[m0 + ar1]; }
    else            { ga0 = (long)(m0 + ar0);       ga1 = (long)(m0 + ar1); }
    const ushort* pa0 = A + ga0 * lda + kc;
    const ushort* pa1 = A + ga1 * lda + kc;
    const ushort* pb0 = B + (long)(n0 + ar0) * ldb + kc;
    const ushort* pb1 = B + (long)(n0 + ar1) * ldb + kc;
    const int wm = w & 1, wn = w >> 1;
    const int lrow = l & 15, quad = l >> 4;

    // prologue: stage k=0 into half 0
    {
        ushort* d0 = lds + c0 * 512;
        ushort* d1 = lds + c1 * 512;
        async16(pa0, d0); async16(pa1, d1);
        async16(pb0, d0 + 4096); async16(pb1, d1 + 4096);
    }
    int cur = 0;
    for (int kt = 0; kt < K; kt += 32) {
        __syncthreads();                     // half `cur` staged (vmcnt drained here)
        if (kt + 32 < K) {                   // prefetch next tile into other half
            pa0 += 32; pa1 += 32; pb0 += 32; pb1 += 32;
            ushort* e0 = lds + (cur ^ 1) * 8192 + c0 * 512;
            ushort* e1 = lds + (cur ^ 1) * 8192 + c1 * 512;
            async16(pa0, e0); async16(pa1, e1);
            async16(pb0, e0 + 4096); async16(pb1, e1 + 4096);
        }
        const ushort* As = lds + cur * 8192;
        const ushort* Bs = As + 4096;
        bf16x8_t a[4], b[4];
#pragma unroll
        for (int mi = 0; mi < 4; mi++)
            a[mi] = *(const bf16x8_t*)(As + (wm * 64 + mi * 16 + lrow) * 32 + quad * 8);
#pragma unroll
        for (int ni = 0; ni < 4; ni++)
            b[ni] = *(const bf16x8_t*)(Bs + (wn * 64 + ni * 16 + lrow) * 32 + quad * 8);
#pragma unroll
        for (int mi = 0; mi < 4; mi++)
#pragma unroll
            for (int ni = 0; ni < 4; ni++)
                acc[mi][ni] = __builtin_amdgcn_mfma_f32_16x16x32_bf16(a[mi], b[ni], acc[mi][ni], 0, 0, 0);
        cur ^= 1;
    }
}

// MODE 0: silu -> bf16 store (shared GEMM1, z over S). MODE 2: f32 store (shared GEMM2).
template<int MODE>
__global__ __launch_bounds__(256, 3) void gemm_dense(const ushort* __restrict__ A, const ushort* __restrict__ B,
                                                     void* __restrict__ C, int lda, int ldb, int ldc, int K,
                                                     long bStride, int cZOff) {
    __shared__ ushort lds[16384];
    int m0 = blockIdx.x * 128, n0 = blockIdx.y * 128;
    const ushort* Bz = B + (long)blockIdx.z * bStride;
    f32x4_t acc[4][4];
#pragma unroll
    for (int mi = 0; mi < 4; mi++)
#pragma unroll
        for (int ni = 0; ni < 4; ni++) acc[mi][ni] = (f32x4_t){0.f, 0.f, 0.f, 0.f};
    gemm_tile_core<false>(A, Bz, lda, ldb, K, m0, n0, nullptr, acc, lds);

    const int w = threadIdx.x >> 6, l = threadIdx.x & 63;
    const int wm = w & 1, wn = w >> 1, quad = l >> 4, lcol = l & 15;
    int colBase = (int)blockIdx.z * cZOff + n0 + wn * 64;
#pragma unroll
    for (int mi = 0; mi < 4; mi++) {
        int rowb = m0 + wm * 64 + mi * 16 + quad * 4;
#pragma unroll
        for (int ni = 0; ni < 4; ni++) {
            int col = colBase + ni * 16 + lcol;
#pragma unroll
            for (int r = 0; r < 4; r++) {
                float v = acc[mi][ni][r];
                if (MODE == 0) ((ushort*)C)[(long)(rowb + r) * ldc + col] = f2bf(silu(v));
                else           ((float*)C)[(long)(rowb + r) * ldc + col] = v;
            }
        }
    }
}

// MODE 1: routed GEMM1 — A rows gathered via slot_token, silu -> bf16 to hg (slot-major).
// MODE 3: routed GEMM2 — A = hg direct; epilogue stores w_slot * acc as bf16 into ro[slot]
//         (plain stores; combine_kernel gathers per token afterwards — NO atomics).
template<int MODE>
__global__ __launch_bounds__(256, 3) void gemm_grouped(const ushort* __restrict__ A, const ushort* __restrict__ B,
                                                       void* __restrict__ C, int lda, int ldb, int ldc, int K,
                                                       long bExpertStride,
                                                       const int* __restrict__ tile_expert,
                                                       const int* __restrict__ tile_row,
                                                       const int* __restrict__ meta,
                                                       const int* __restrict__ slot_token,
                                                       const float* __restrict__ slot_w) {
    if ((int)blockIdx.x >= meta[0]) return;
    __shared__ ushort lds[16384];
    int e = tile_expert[blockIdx.x];
    int m0 = tile_row[blockIdx.x];
    int n0 = blockIdx.y * 128;
    const ushort* Be = B + (long)e * bExpertStride;
    f32x4_t acc[4][4];
#pragma unroll
    for (int mi = 0; mi < 4; mi++)
#pragma unroll
        for (int ni = 0; ni < 4; ni++) acc[mi][ni] = (f32x4_t){0.f, 0.f, 0.f, 0.f};
    gemm_tile_core<MODE == 1>(A, Be, lda, ldb, K, m0, n0, slot_token, acc, lds);

    const int w = threadIdx.x >> 6, l = threadIdx.x & 63;
    const int wm = w & 1, wn = w >> 1, quad = l >> 4, lcol = l & 15;
#pragma unroll
    for (int mi = 0; mi < 4; mi++) {
        int rowb = m0 + wm * 64 + mi * 16 + quad * 4;
#pragma unroll
        for (int ni = 0; ni < 4; ni++) {
            int col = n0 + wn * 64 + ni * 16 + lcol;
#pragma unroll
            for (int r = 0; r < 4; r++) {
                float v = acc[mi][ni][r];
                int row = rowb + r;
                if (MODE == 1) {
                    ((ushort*)C)[(long)row * ldc + col] = f2bf(silu(v));
                } else {
                    float wt = slot_w[row];            // 0 for pad slots
                    ((ushort*)C)[(long)row * ldc + col] = f2bf(v * wt);
                }
            }
        }
    }
}

// out[t,:] += ro[slot1(t),:] + ro[slot2(t),:]   (weights already folded into ro)
__global__ __launch_bounds__(256) void combine_kernel(float* __restrict__ out, const ushort* __restrict__ ro,
                                                      const int* __restrict__ slot_of) {
    int t = blockIdx.x;
    int s1 = slot_of[t * 2], s2 = slot_of[t * 2 + 1];
    const u16x8_t* r1 = (const u16x8_t*)(ro + (size_t)s1 * DMODEL);
    const u16x8_t* r2 = (const u16x8_t*)(ro + (size_t)s2 * DMODEL);
    int i = threadIdx.x;                      // DMODEL/8 = 256 exactly
    u16x8_t a = r1[i], b = r2[i];
    float4* o = (float4*)(out + (size_t)t * DMODEL) + i * 2;
    float4 o0 = o[0], o1 = o[1];
    o0.x += bf2f(a[0]) + bf2f(b[0]); o0.y += bf2f(a[1]) + bf2f(b[1]);
    o0.z += bf2f(a[2]) + bf2f(b[2]); o0.w += bf2f(a[3]) + bf2f(b[3]);
    o1.x += bf2f(a[4]) + bf2f(b[4]); o1.y += bf2f(a[5]) + bf2f(b[5]);
    o1.z += bf2f(a[6]) + bf2f(b[6]); o1.w += bf2f(a[7]) + bf2f(b[7]);
    o[0] = o0; o[1] = o1;
}

// ---------------- launch ----------------

extern "C" void kernel_launch(void* const* d_in, const int* in_sizes, int n_in,
                              void* d_out, int out_size, void* d_ws, size_t ws_size,
                              hipStream_t stream) {
    const float* x   = (const float*)d_in[0];
    const float* gw  = (const float*)d_in[1];
    const float* sw1 = (const float*)d_in[2];
    const float* sw2 = (const float*)d_in[3];
    const float* ew1 = (const float*)d_in[4];
    const float* ew2 = (const float*)d_in[5];
    float* out = (float*)d_out;

    char* p = (char*)d_ws;
    auto alloc = [&](size_t bytes) { char* r = p; p += (bytes + 511) & ~(size_t)511; return r; };
    ushort* xb    = (ushort*)alloc((size_t)T_TOT * DMODEL * 2);
    ushort* w1t   = (ushort*)alloc((size_t)2 * HDIM * DMODEL * 2);
    ushort* w2t   = (ushort*)alloc((size_t)DMODEL * 2 * HDIM * 2);
    ushort* ew1t  = (ushort*)alloc((size_t)NEXP * HDIM * DMODEL * 2);
    ushort* ew2t  = (ushort*)alloc((size_t)NEXP * DMODEL * HDIM * 2);
    ushort* h     = (ushort*)alloc((size_t)T_TOT * 2 * HDIM * 2);
    ushort* hg    = (ushort*)alloc((size_t)MAXSLOT * HDIM * 2);
    ushort* ro    = (ushort*)alloc((size_t)MAXSLOT * DMODEL * 2);   // routed weighted rows, bf16
    int*    slot_token = (int*)alloc(MAXSLOT * 4);
    float*  slot_w     = (float*)alloc(MAXSLOT * 4);
    int*    slot_of    = (int*)alloc(T_TOT * 2 * 4);
    int*    topk_idx   = (int*)alloc(T_TOT * 2 * 4);
    float*  topk_w     = (float*)alloc(T_TOT * 2 * 4);
    int*    cnt        = (int*)alloc(64);
    int*    cursor     = (int*)alloc(64);
    int*    tile_expert= (int*)alloc(512);
    int*    tile_row   = (int*)alloc(512);
    int*    meta       = (int*)alloc(64);
    double* probs_sum  = (double*)alloc(128);
    double* logits_sum = (double*)alloc(128);

    init_kernel<<<1, 64, 0, stream>>>(cnt, probs_sum, logits_sum);
    cvt_bf16<<<(T_TOT * DMODEL) / 1024, 256, 0, stream>>>(x, xb);
    // shared_w1 [2,2048,1408] -> w1t [2,1408,2048]
    transpose_cvt<<<dim3(HDIM / 64, DMODEL / 64, 2), 256, 0, stream>>>(
        sw1, w1t, DMODEL, HDIM, (long)DMODEL * HDIM, (long)HDIM * DMODEL, DMODEL);
    // shared_w2 [2,1408,2048] -> w2t [2048, 2*1408]
    transpose_cvt<<<dim3(DMODEL / 64, HDIM / 64, 2), 256, 0, stream>>>(
        sw2, w2t, HDIM, DMODEL, (long)HDIM * DMODEL, (long)HDIM, 2 * HDIM);
    // expert_w1 [16,2048,1408] -> ew1t [16,1408,2048]
    transpose_cvt<<<dim3(HDIM / 64, DMODEL / 64, NEXP), 256, 0, stream>>>(
        ew1, ew1t, DMODEL, HDIM, (long)DMODEL * HDIM, (long)HDIM * DMODEL, DMODEL);
    // expert_w2 [16,1408,2048] -> ew2t [16,2048,1408]
    transpose_cvt<<<dim3(DMODEL / 64, HDIM / 64, NEXP), 256, 0, stream>>>(
        ew2, ew2t, HDIM, DMODEL, (long)HDIM * DMODEL, (long)DMODEL * HDIM, HDIM);

    router_kernel<<<T_TOT / 4, 256, 0, stream>>>(x, gw, topk_idx, topk_w, probs_sum, logits_sum, cnt);
    setup_kernel<<<1, 256, 0, stream>>>(cnt, cursor, tile_expert, tile_row, meta,
                                        slot_token, slot_w, probs_sum, logits_sum, out + (size_t)T_TOT * DMODEL);
    scatter_kernel<<<T_TOT / 256, 256, 0, stream>>>(topk_idx, topk_w, cursor, slot_token, slot_w, slot_of);

    // shared GEMM1: h[t, s*1408+j] = silu(xb @ w1t[s]^T)
    gemm_dense<0><<<dim3(T_TOT / 128, HDIM / 128, 2), 256, 0, stream>>>(
        xb, w1t, h, DMODEL, DMODEL, 2 * HDIM, DMODEL, (long)HDIM * DMODEL, HDIM);
    // routed GEMM1: hg[slot, j] = silu(x[slot_token] @ ew1t[e]^T)
    gemm_grouped<1><<<dim3(MAXTILE, HDIM / 128), 256, 0, stream>>>(
        xb, ew1t, hg, DMODEL, DMODEL, HDIM, DMODEL, (long)HDIM * DMODEL,
        tile_expert, tile_row, meta, slot_token, slot_w);
    // shared GEMM2: out[t,d] = h @ w2t^T  (K = 2816 spans both shared experts)
    gemm_dense<2><<<dim3(T_TOT / 128, DMODEL / 128, 1), 256, 0, stream>>>(
        h, w2t, out, 2 * HDIM, 2 * HDIM, DMODEL, 2 * HDIM, 0L, 0);
    // routed GEMM2: ro[slot,d] = w_slot * (hg @ ew2t[e]^T)   — plain bf16 stores
    gemm_grouped<3><<<dim3(MAXTILE, DMODEL / 128), 256, 0, stream>>>(
        hg, ew2t, ro, HDIM, HDIM, DMODEL, HDIM, (long)DMODEL * HDIM,
        tile_expert, tile_row, meta, slot_token, slot_w);
    // combine: out[t] += ro[slot1(t)] + ro[slot2(t)]
    combine_kernel<<<T_TOT, 256, 0, stream>>>(out, ro, slot_of);
}